// Round 1
// baseline (8117.995 us; speedup 1.0000x reference)
//
#include <hip/hip_runtime.h>
#include <hip/hip_fp16.h>

#define NS 132      // number of HMM states
#define NA 126      // alphabet size
#define BPAD 127    // padded row length for emission matrix in LDS (bank spread)
#define TLEN 10000
#define NBATCH 32

// ---------------------------------------------------------------------------
// Kernel 1: one-hot [B*T, 126] fp32 -> index [B*T] int
// One wave (64 lanes) per (b,t) position; coalesced loads + ballot/ctz.
// ---------------------------------------------------------------------------
__global__ void onehot_to_idx_kernel(const float* __restrict__ x,
                                     int* __restrict__ obs, int total) {
    int wid  = (int)((blockIdx.x * blockDim.x + threadIdx.x) >> 6);
    int lane = threadIdx.x & 63;
    if (wid >= total) return;
    const float* row = x + (size_t)wid * NA;
    float v0 = row[lane];                                  // cols 0..63
    float v1 = (lane < NA - 64) ? row[64 + lane] : 0.0f;   // cols 64..125
    unsigned long long b0 = __ballot(v0 > 0.5f);
    unsigned long long b1 = __ballot(v1 > 0.5f);
    int idx;
    if (b0) idx = __ffsll(b0) - 1;
    else    idx = 64 + (__ffsll(b1) - 1);
    if (lane == 0) obs[wid] = idx;
}

// ---------------------------------------------------------------------------
// Kernel 2: serial HMM forward scan. One block per batch row.
// Thread j holds column A[:,j] in registers; alpha double-buffered in LDS;
// emission matrix in LDS as f16; normalization deferred to every 4th step.
// ---------------------------------------------------------------------------
__global__ __launch_bounds__(192) void hmm_forward_kernel(
    const float* __restrict__ A,    // [132][132] row-stochastic
    const float* __restrict__ Bm,   // [132][126]
    const float* __restrict__ I0,   // [132]
    const int*   __restrict__ obs,  // [32][10000]
    float*       __restrict__ out)  // [32]
{
    __shared__ __half sB[NS * BPAD];     // ~33 KB
    __shared__ float  sAlpha[2][NS];     // double buffer, 16B-aligned rows (132%4==0)
    __shared__ float  sPart[4];          // per-wave partial sums (3 used)

    const int  tid    = threadIdx.x;
    const int  b      = blockIdx.x;
    const int  j      = (tid < NS) ? tid : (NS - 1);  // clamped state index
    const bool active = (tid < NS);
    const int  lane   = tid & 63;
    const int  wv     = tid >> 6;

    // Stage emission matrix into LDS (f16, padded rows)
    for (int idx = tid; idx < NS * NA; idx += 192) {
        int r = idx / NA;
        int c = idx - r * NA;
        sB[r * BPAD + c] = __float2half(Bm[idx]);
    }

    // Load A column j into registers (coalesced across threads)
    float rA[NS];
#pragma unroll
    for (int i = 0; i < NS; ++i) rA[i] = A[i * NS + j];

    const int* ob = obs + b * TLEN;
    int   o0  = ob[0];
    float i0v = active ? I0[j] : 0.0f;
    __syncthreads();

    // t = 0: alpha0 = I0 * B[:, o0]; c0 = sum; ll = log(c0)
    float aj = active ? (i0v * __half2float(sB[j * BPAD + o0])) : 0.0f;
    float ws = aj;
#pragma unroll
    for (int off = 32; off > 0; off >>= 1) ws += __shfl_xor(ws, off, 64);
    if (lane == 0) sPart[wv] = ws;
    __syncthreads();
    float c  = sPart[0] + sPart[1] + sPart[2];
    float ll = __logf(c);
    if (active) sAlpha[0][j] = aj / c;
    __syncthreads();

    int cur   = 0;
    int o_nxt = ob[1];

    for (int t = 1; t < TLEN; ++t) {
        const int o = o_nxt;
        if (t + 1 < TLEN) o_nxt = ob[t + 1];           // prefetch next obs (uniform)

        const float em = __half2float(sB[j * BPAD + o]); // emission, conflict-free

        // dot(alpha, A[:,j]) -- 33 broadcast ds_read_b128 + 132 FMA, 4 chains
        const float4* a4 = (const float4*)(&sAlpha[cur][0]);
        float s0 = 0.f, s1 = 0.f, s2 = 0.f, s3 = 0.f;
#pragma unroll
        for (int i4 = 0; i4 < NS / 4; ++i4) {
            float4 av = a4[i4];
            s0 = fmaf(av.x, rA[4 * i4 + 0], s0);
            s1 = fmaf(av.y, rA[4 * i4 + 1], s1);
            s2 = fmaf(av.z, rA[4 * i4 + 2], s2);
            s3 = fmaf(av.w, rA[4 * i4 + 3], s3);
        }
        float a = ((s0 + s1) + (s2 + s3)) * em;
        if (!active) a = 0.0f;

        if ((t & 3) == 0 || t == TLEN - 1) {
            // renormalize: block reduction -> c, ll += log(c), alpha /= c
            float w2 = a;
#pragma unroll
            for (int off = 32; off > 0; off >>= 1) w2 += __shfl_xor(w2, off, 64);
            if (lane == 0) sPart[wv] = w2;
            __syncthreads();
            float c2 = sPart[0] + sPart[1] + sPart[2];
            ll += __logf(c2);
            if (active) sAlpha[cur ^ 1][j] = a * (1.0f / c2);
            __syncthreads();
        } else {
            // deferred normalization: just hand the unnormalized alpha forward
            if (active) sAlpha[cur ^ 1][j] = a;
            __syncthreads();
        }
        cur ^= 1;
    }

    if (tid == 0) out[b] = ll;
}

// ---------------------------------------------------------------------------
extern "C" void kernel_launch(void* const* d_in, const int* in_sizes, int n_in,
                              void* d_out, int out_size, void* d_ws, size_t ws_size,
                              hipStream_t stream) {
    const float* x  = (const float*)d_in[0];  // [32,10000,126] one-hot fp32
    const float* A  = (const float*)d_in[1];  // [132,132]
    const float* Bm = (const float*)d_in[2];  // [132,126]
    const float* I0 = (const float*)d_in[3];  // [132]
    float* out = (float*)d_out;               // [32] fp32
    int*   obs = (int*)d_ws;                  // [32*10000] scratch

    const int total = NBATCH * TLEN;          // 320000 wave-tasks
    const int waves_per_block = 256 / 64;
    const int blocks = (total + waves_per_block - 1) / waves_per_block;
    onehot_to_idx_kernel<<<blocks, 256, 0, stream>>>(x, obs, total);
    hmm_forward_kernel<<<NBATCH, 192, 0, stream>>>(A, Bm, I0, obs, out);
}

// Round 2
// 6618.584 us; speedup vs baseline: 1.2265x; 1.2265x over previous
//
#include <hip/hip_runtime.h>

// ---------------------------------------------------------------------------
// Scaled HMM forward, B=32 rows, T=10000 serial steps, N=132 states.
// Design: one block per batch row (latency-bound serial scan).
//  - A packed as f16 pairs in VGPRs (v_dot2_f32_f16: 2 MACs/instr)
//  - alpha (f16, normalized each step) in LDS, broadcast ds_read_b128
//  - c_t computed redundantly per-thread via precomputed D[o] = A @ B[:,o]
//    => no cross-thread reduction, ONE barrier per step
//  - each dot split across lane pairs (l, l^32); combine via shfl_xor(32)
//  - __launch_bounds__(320,1): occupancy is irrelevant (32 blocks on 256 CUs),
//    so let the allocator use as many VGPRs as it wants (round-1 failure:
//    VGPR_Count=84 => A column spilled, dot fed from scratch memory)
// ---------------------------------------------------------------------------

typedef _Float16 half_t;
typedef half_t h2 __attribute__((ext_vector_type(2)));

#define FDOT2(a, b, acc) __builtin_amdgcn_fdot2((a), (b), (acc), false)

#define NS 132
#define NA 126
#define NI2 66         // NS/2 (h2 pairs per full dot)
#define DPAD 136       // padded row length (halves) for D rows / alpha buffers
#define TLEN 10000
#define NBATCH 32

// workspace layout (bytes); total ~742 KB (round 1 proved >=1.28MB usable)
#define OBS_OFF 0         // 32*10000 ushort = 640000
#define AH_OFF  640000    // 66*132 h2 (4B)  = 34848
#define BT_OFF  674848    // 126*132 half    = 33264
#define DH_OFF  708112    // 126*136 half    = 34272

// ---------------------------------------------------------------------------
// one-hot [B*T, 126] fp32 -> index [B*T] ushort. One wave per (b,t).
// ---------------------------------------------------------------------------
__global__ void onehot_to_idx_kernel(const float* __restrict__ x,
                                     unsigned short* __restrict__ obs, int total) {
    int wid  = (int)((blockIdx.x * blockDim.x + threadIdx.x) >> 6);
    int lane = threadIdx.x & 63;
    if (wid >= total) return;
    const float* row = x + (size_t)wid * NA;
    float v0 = row[lane];
    float v1 = (lane < NA - 64) ? row[64 + lane] : 0.0f;
    unsigned long long b0 = __ballot(v0 > 0.5f);
    unsigned long long b1 = __ballot(v1 > 0.5f);
    int idx = b0 ? (__ffsll(b0) - 1) : (64 + __ffsll(b1) - 1);
    if (lane == 0) obs[wid] = (unsigned short)idx;
}

// ---------------------------------------------------------------------------
// Ah[i2*NS + j] = (f16(A[2*i2][j]), f16(A[2*i2+1][j]))
// ---------------------------------------------------------------------------
__global__ void pack_A_kernel(const float* __restrict__ A, h2* __restrict__ Ah) {
    int idx = blockIdx.x * 256 + threadIdx.x;
    if (idx >= NI2 * NS) return;
    int i2 = idx / NS, j = idx % NS;
    h2 v = {(half_t)A[(2 * i2) * NS + j], (half_t)A[(2 * i2 + 1) * NS + j]};
    Ah[idx] = v;
}

// ---------------------------------------------------------------------------
// Bt[o*NS + j] = f16(B[j*NA + o])   (transposed emission, f16)
// ---------------------------------------------------------------------------
__global__ void pack_Bt_kernel(const float* __restrict__ B, half_t* __restrict__ Bt) {
    int idx = blockIdx.x * 256 + threadIdx.x;
    if (idx >= NA * NS) return;
    int o = idx / NS, j = idx % NS;
    Bt[idx] = (half_t)B[j * NA + o];
}

// ---------------------------------------------------------------------------
// Dh[o*DPAD + i] = f16( sum_j A[i][j] * B[j][o] ), pad [132..135] = 0
// ---------------------------------------------------------------------------
__global__ void make_D_kernel(const float* __restrict__ A, const float* __restrict__ B,
                              half_t* __restrict__ Dh) {
    __shared__ float bcol[NS];
    int o = blockIdx.x, i = threadIdx.x;
    if (i < NS) bcol[i] = B[i * NA + o];
    __syncthreads();
    if (i < DPAD) {
        if (i < NS) {
            float s = 0.f;
#pragma unroll 4
            for (int jr = 0; jr < NS; ++jr) s += A[i * NS + jr] * bcol[jr];
            Dh[o * DPAD + i] = (half_t)s;
        } else {
            Dh[o * DPAD + i] = (half_t)0.f;
        }
    }
}

// ---------------------------------------------------------------------------
// The serial scan. 32 blocks x 320 threads (5 waves).
// Thread (j, h): j = wave*32 + (lane&31) owns state j; h = lane>>5 owns half
// of the K-range: h0 -> i2 in {0..31, 64, 65}; h1 -> i2 in {32..63}.
// ---------------------------------------------------------------------------
__global__ __launch_bounds__(320, 1) void hmm_forward_kernel(
    const h2* __restrict__ Ah,
    const half_t* __restrict__ Bt,
    const half_t* __restrict__ Dh,
    const float* __restrict__ I0,
    const unsigned short* __restrict__ obs,
    float* __restrict__ out)
{
    __shared__ __align__(16) half_t sD[NA * DPAD];   // 34272 B
    __shared__ __align__(16) half_t sAl[2][DPAD];    // alpha double buffer (f16)
    __shared__ float sPart[5];

    const int tid = threadIdx.x;
    const int b   = blockIdx.x;
    const int l   = tid & 63;
    const int w   = tid >> 6;
    const int h   = l >> 5;
    const int jj  = w * 32 + (l & 31);
    const bool active = (jj < NS);
    const int j   = active ? jj : (NS - 1);

    // stage D table into LDS (2142 float4)
    {
        const float4* src = (const float4*)Dh;
        float4* dst = (float4*)sD;
        for (int k = tid; k < (NA * DPAD * 2) / 16; k += 320) dst[k] = src[k];
    }
    if (tid < 4) { sAl[0][NS + tid] = (half_t)0.f; sAl[1][NS + tid] = (half_t)0.f; }

    // A-column fragments for this thread's half of the dot
    h2 rA[34];
    if (h == 0) {
#pragma unroll
        for (int k = 0; k < 32; ++k) rA[k] = Ah[k * NS + j];
        rA[32] = Ah[64 * NS + j];
        rA[33] = Ah[65 * NS + j];
    } else {
#pragma unroll
        for (int k = 0; k < 32; ++k) rA[k] = Ah[(32 + k) * NS + j];
        h2 z = {(half_t)0.f, (half_t)0.f};
        rA[32] = z;
        rA[33] = z;
    }

    const unsigned short* ob = obs + b * TLEN;
    const int boff = h ? 128 : 0;   // byte offset of this half's 8 b128 chunks
    const int toff = h ? 264 : 256; // byte offset of this half's tail float2
                                    // (h1 tail lands in the zeroed pad: contributes 0)

    int o0 = (int)ob[0];
    int o1 = (int)ob[1];
    float i0 = (active && h == 0) ? I0[j] : 0.f;
    __syncthreads();

    // ---- t = 0: alpha0 = I0 * B[:,o0]; c0 by one full block reduction ----
    float em = (float)Bt[o0 * NS + j];
    float a0 = i0 * em;
    float r = a0;
#pragma unroll
    for (int off = 32; off; off >>= 1) r += __shfl_xor(r, off, 64);
    if (l == 0) sPart[w] = r;
    __syncthreads();
    float c0 = sPart[0] + sPart[1] + sPart[2] + sPart[3] + sPart[4];
    float ll = __logf(c0);
    if (active && h == 0) sAl[0][j] = (half_t)(a0 / c0);

    // prefetch operands for t = 1
    em = (float)Bt[o1 * NS + j];
    float4 dv[8];
    float2 dt;
    {
        const char* drow = (const char*)&sD[o1 * DPAD];
#pragma unroll
        for (int q = 0; q < 8; ++q) dv[q] = *(const float4*)(drow + boff + 16 * q);
        dt = *(const float2*)(drow + toff);
    }
    int o_nx = (int)ob[2];
    __syncthreads();

    int cur = 0;
    float lp = 1.0f;

    for (int t = 1; t < TLEN; ++t) {
        const char* arow = (const char*)&sAl[cur][0];
        float s0 = 0.f, s1 = 0.f, s2 = 0.f, s3 = 0.f;   // a_j dot (A column)
        float u0 = 0.f, u1 = 0.f, u2 = 0.f, u3 = 0.f;   // c dot (D row)
#pragma unroll
        for (int q = 0; q < 8; ++q) {
            float4 av = *(const float4*)(arow + boff + 16 * q);
            h2 x0 = __builtin_bit_cast(h2, av.x);
            h2 x1 = __builtin_bit_cast(h2, av.y);
            h2 x2 = __builtin_bit_cast(h2, av.z);
            h2 x3 = __builtin_bit_cast(h2, av.w);
            h2 d0 = __builtin_bit_cast(h2, dv[q].x);
            h2 d1 = __builtin_bit_cast(h2, dv[q].y);
            h2 d2 = __builtin_bit_cast(h2, dv[q].z);
            h2 d3 = __builtin_bit_cast(h2, dv[q].w);
            s0 = FDOT2(x0, rA[4 * q + 0], s0);
            s1 = FDOT2(x1, rA[4 * q + 1], s1);
            s2 = FDOT2(x2, rA[4 * q + 2], s2);
            s3 = FDOT2(x3, rA[4 * q + 3], s3);
            u0 = FDOT2(x0, d0, u0);
            u1 = FDOT2(x1, d1, u1);
            u2 = FDOT2(x2, d2, u2);
            u3 = FDOT2(x3, d3, u3);
        }
        {
            float2 at = *(const float2*)(arow + toff);
            h2 xa = __builtin_bit_cast(h2, at.x);
            h2 xb = __builtin_bit_cast(h2, at.y);
            h2 da = __builtin_bit_cast(h2, dt.x);
            h2 db = __builtin_bit_cast(h2, dt.y);
            s0 = FDOT2(xa, rA[32], s0);
            s1 = FDOT2(xb, rA[33], s1);
            u0 = FDOT2(xa, da, u0);
            u1 = FDOT2(xb, db, u1);
        }
        float s = (s0 + s1) + (s2 + s3);
        float c = (u0 + u1) + (u2 + u3);
        s += __shfl_xor(s, 32, 64);   // combine the two K-halves
        c += __shfl_xor(c, 32, 64);

        lp *= c;                              // c identical across all threads
        if ((t & 3) == 0) { ll += __logf(lp); lp = 1.f; }
        float anew = s * em * (1.0f / c);

        // prefetch operands for t+1 (independent of this step's barrier)
        em = (float)Bt[o_nx * NS + j];
        const char* drow = (const char*)&sD[o_nx * DPAD];
#pragma unroll
        for (int q = 0; q < 8; ++q) dv[q] = *(const float4*)(drow + boff + 16 * q);
        dt = *(const float2*)(drow + toff);
        o_nx = (t + 2 < TLEN) ? (int)ob[t + 2] : 0;

        if (active && h == 0) sAl[cur ^ 1][j] = (half_t)anew;
        __syncthreads();
        cur ^= 1;
    }

    ll += __logf(lp);
    if (tid == 0) out[b] = ll;
}

// ---------------------------------------------------------------------------
extern "C" void kernel_launch(void* const* d_in, const int* in_sizes, int n_in,
                              void* d_out, int out_size, void* d_ws, size_t ws_size,
                              hipStream_t stream) {
    const float* x  = (const float*)d_in[0];  // [32,10000,126] one-hot fp32
    const float* A  = (const float*)d_in[1];  // [132,132]
    const float* Bm = (const float*)d_in[2];  // [132,126]
    const float* I0 = (const float*)d_in[3];  // [132]
    float* out = (float*)d_out;               // [32] fp32

    char* ws = (char*)d_ws;
    unsigned short* obs = (unsigned short*)(ws + OBS_OFF);
    h2*     Ah = (h2*)(ws + AH_OFF);
    half_t* Bt = (half_t*)(ws + BT_OFF);
    half_t* Dh = (half_t*)(ws + DH_OFF);

    const int total = NBATCH * TLEN;
    onehot_to_idx_kernel<<<(total + 3) / 4, 256, 0, stream>>>(x, obs, total);
    pack_A_kernel<<<(NI2 * NS + 255) / 256, 256, 0, stream>>>(A, Ah);
    pack_Bt_kernel<<<(NA * NS + 255) / 256, 256, 0, stream>>>(Bm, Bt);
    make_D_kernel<<<NA, 192, 0, stream>>>(A, Bm, Dh);
    hmm_forward_kernel<<<NBATCH, 320, 0, stream>>>(Ah, Bt, Dh, I0, obs, out);
}

// Round 3
// 6423.306 us; speedup vs baseline: 1.2638x; 1.0304x over previous
//
#include <hip/hip_runtime.h>

// ---------------------------------------------------------------------------
// Scaled HMM forward, B=32 rows, T=10000 serial steps, N=132 states.
// One block per batch row (latency-bound serial scan).
//  - A packed as f16 pairs in VGPRs (v_dot2_f32_f16: 2 MACs/instr)
//  - alpha (f16, normalized each step) in LDS, broadcast ds_read_b128
//  - c_t computed redundantly per-thread via precomputed D[o] = A @ B[:,o]
//    => no cross-thread reduction, ONE barrier per step
//  - each dot split across lane pairs (l, l^32); combine via shfl_xor(32)
//  - ROUND-3 FIX: rounds 1-2 failed on register residency (VGPR_Count 84/52:
//    rA + dv spilled/rematerialized every step -> 4x VALU bloat).
//    amdgpu_waves_per_eu(1,2) raises the allocator budget to 256 VGPRs;
//    empty keep-alive asm pins rA (loop top) and the dv/em prefetch
//    (pre-barrier) into registers.
// ---------------------------------------------------------------------------

typedef _Float16 half_t;
typedef half_t h2 __attribute__((ext_vector_type(2)));

#define FDOT2(a, b, acc) __builtin_amdgcn_fdot2((a), (b), (acc), false)
#define KEEP(x) asm volatile("" : "+v"(x))

#define NS 132
#define NA 126
#define NI2 66         // NS/2 (h2 pairs per full dot)
#define DPAD 136       // padded row length (halves) for D rows / alpha buffers
#define TLEN 10000
#define NBATCH 32

// workspace layout (bytes)
#define OBS_OFF 0         // 32*10000 ushort = 640000
#define AH_OFF  640000    // 66*132 h2 (4B)  = 34848
#define BT_OFF  674848    // 126*132 half    = 33264
#define DH_OFF  708112    // 126*136 half    = 34272

// ---------------------------------------------------------------------------
// one-hot [B*T, 126] fp32 -> index [B*T] ushort. One wave per (b,t).
// ---------------------------------------------------------------------------
__global__ void onehot_to_idx_kernel(const float* __restrict__ x,
                                     unsigned short* __restrict__ obs, int total) {
    int wid  = (int)((blockIdx.x * blockDim.x + threadIdx.x) >> 6);
    int lane = threadIdx.x & 63;
    if (wid >= total) return;
    const float* row = x + (size_t)wid * NA;
    float v0 = row[lane];
    float v1 = (lane < NA - 64) ? row[64 + lane] : 0.0f;
    unsigned long long b0 = __ballot(v0 > 0.5f);
    unsigned long long b1 = __ballot(v1 > 0.5f);
    int idx = b0 ? (__ffsll(b0) - 1) : (64 + __ffsll(b1) - 1);
    if (lane == 0) obs[wid] = (unsigned short)idx;
}

__global__ void pack_A_kernel(const float* __restrict__ A, h2* __restrict__ Ah) {
    int idx = blockIdx.x * 256 + threadIdx.x;
    if (idx >= NI2 * NS) return;
    int i2 = idx / NS, j = idx % NS;
    h2 v = {(half_t)A[(2 * i2) * NS + j], (half_t)A[(2 * i2 + 1) * NS + j]};
    Ah[idx] = v;
}

__global__ void pack_Bt_kernel(const float* __restrict__ B, half_t* __restrict__ Bt) {
    int idx = blockIdx.x * 256 + threadIdx.x;
    if (idx >= NA * NS) return;
    int o = idx / NS, j = idx % NS;
    Bt[idx] = (half_t)B[j * NA + o];
}

__global__ void make_D_kernel(const float* __restrict__ A, const float* __restrict__ B,
                              half_t* __restrict__ Dh) {
    __shared__ float bcol[NS];
    int o = blockIdx.x, i = threadIdx.x;
    if (i < NS) bcol[i] = B[i * NA + o];
    __syncthreads();
    if (i < DPAD) {
        if (i < NS) {
            float s = 0.f;
#pragma unroll 4
            for (int jr = 0; jr < NS; ++jr) s += A[i * NS + jr] * bcol[jr];
            Dh[o * DPAD + i] = (half_t)s;
        } else {
            Dh[o * DPAD + i] = (half_t)0.f;
        }
    }
}

// ---------------------------------------------------------------------------
// The serial scan. 32 blocks x 320 threads (5 waves).
// Thread (j, h): j = wave*32 + (lane&31) owns state j; h = lane>>5 owns half
// of the K-range: h0 -> i2 in {0..31, 64, 65}; h1 -> i2 in {32..63}.
// ---------------------------------------------------------------------------
__global__ __launch_bounds__(320)
__attribute__((amdgpu_waves_per_eu(1, 2)))
void hmm_forward_kernel(
    const h2* __restrict__ Ah,
    const half_t* __restrict__ Bt,
    const half_t* __restrict__ Dh,
    const float* __restrict__ I0,
    const unsigned short* __restrict__ obs,
    float* __restrict__ out)
{
    __shared__ __align__(16) half_t sD[NA * DPAD];   // 34272 B
    __shared__ __align__(16) half_t sAl[2][DPAD];    // alpha double buffer (f16)
    __shared__ float sPart[5];

    const int tid = threadIdx.x;
    const int b   = blockIdx.x;
    const int l   = tid & 63;
    const int w   = tid >> 6;
    const int h   = l >> 5;
    const int jj  = w * 32 + (l & 31);
    const bool active = (jj < NS);
    const int j   = active ? jj : (NS - 1);

    // stage D table into LDS (2142 float4)
    {
        const float4* src = (const float4*)Dh;
        float4* dst = (float4*)sD;
        for (int k = tid; k < (NA * DPAD * 2) / 16; k += 320) dst[k] = src[k];
    }
    if (tid < 4) { sAl[0][NS + tid] = (half_t)0.f; sAl[1][NS + tid] = (half_t)0.f; }

    // A-column fragments for this thread's half of the dot
    h2 rA[34];
    if (h == 0) {
#pragma unroll
        for (int k = 0; k < 32; ++k) rA[k] = Ah[k * NS + j];
        rA[32] = Ah[64 * NS + j];
        rA[33] = Ah[65 * NS + j];
    } else {
#pragma unroll
        for (int k = 0; k < 32; ++k) rA[k] = Ah[(32 + k) * NS + j];
        h2 z = {(half_t)0.f, (half_t)0.f};
        rA[32] = z;
        rA[33] = z;
    }

    const unsigned short* ob = obs + b * TLEN;
    const int boff = h ? 128 : 0;   // byte offset of this half's 8 b128 chunks
    const int toff = h ? 264 : 256; // byte offset of this half's tail float2
                                    // (h1 tail lands in the zeroed pad: contributes 0)

    int o0 = (int)ob[0];
    int o1 = (int)ob[1];
    float i0 = (active && h == 0) ? I0[j] : 0.f;
    __syncthreads();

    // ---- t = 0: alpha0 = I0 * B[:,o0]; c0 by one full block reduction ----
    float em = (float)Bt[o0 * NS + j];
    float a0 = i0 * em;
    float r = a0;
#pragma unroll
    for (int off = 32; off; off >>= 1) r += __shfl_xor(r, off, 64);
    if (l == 0) sPart[w] = r;
    __syncthreads();
    float c0 = sPart[0] + sPart[1] + sPart[2] + sPart[3] + sPart[4];
    float ll = __logf(c0);
    if (active && h == 0) sAl[0][j] = (half_t)(a0 / c0);

    // prefetch operands for t = 1
    em = (float)Bt[o1 * NS + j];
    float4 dv[8];
    float2 dt;
    {
        const char* drow = (const char*)&sD[o1 * DPAD];
#pragma unroll
        for (int q = 0; q < 8; ++q) dv[q] = *(const float4*)(drow + boff + 16 * q);
        dt = *(const float2*)(drow + toff);
    }
    int o_nx = (int)ob[2];
    __syncthreads();

    int cur = 0;
    float lp = 1.0f;

    for (int t = 1; t < TLEN; ++t) {
        // pin the A-column fragments in VGPRs (defeat rematerialization)
#pragma unroll
        for (int k = 0; k < 34; ++k) KEEP(rA[k]);

        const char* arow = (const char*)&sAl[cur][0];
        float s0 = 0.f, s1 = 0.f, s2 = 0.f, s3 = 0.f;   // a_j dot (A column)
        float u0 = 0.f, u1 = 0.f, u2 = 0.f, u3 = 0.f;   // c dot (D row)
#pragma unroll
        for (int q = 0; q < 8; ++q) {
            float4 av = *(const float4*)(arow + boff + 16 * q);
            h2 x0 = __builtin_bit_cast(h2, av.x);
            h2 x1 = __builtin_bit_cast(h2, av.y);
            h2 x2 = __builtin_bit_cast(h2, av.z);
            h2 x3 = __builtin_bit_cast(h2, av.w);
            h2 d0 = __builtin_bit_cast(h2, dv[q].x);
            h2 d1 = __builtin_bit_cast(h2, dv[q].y);
            h2 d2 = __builtin_bit_cast(h2, dv[q].z);
            h2 d3 = __builtin_bit_cast(h2, dv[q].w);
            s0 = FDOT2(x0, rA[4 * q + 0], s0);
            s1 = FDOT2(x1, rA[4 * q + 1], s1);
            s2 = FDOT2(x2, rA[4 * q + 2], s2);
            s3 = FDOT2(x3, rA[4 * q + 3], s3);
            u0 = FDOT2(x0, d0, u0);
            u1 = FDOT2(x1, d1, u1);
            u2 = FDOT2(x2, d2, u2);
            u3 = FDOT2(x3, d3, u3);
        }
        {
            float2 at = *(const float2*)(arow + toff);
            h2 xa = __builtin_bit_cast(h2, at.x);
            h2 xb = __builtin_bit_cast(h2, at.y);
            h2 da = __builtin_bit_cast(h2, dt.x);
            h2 db = __builtin_bit_cast(h2, dt.y);
            s0 = FDOT2(xa, rA[32], s0);
            s1 = FDOT2(xb, rA[33], s1);
            u0 = FDOT2(xa, da, u0);
            u1 = FDOT2(xb, db, u1);
        }
        float s = (s0 + s1) + (s2 + s3);
        float c = (u0 + u1) + (u2 + u3);
        s += __shfl_xor(s, 32, 64);   // combine the two K-halves
        c += __shfl_xor(c, 32, 64);

        lp *= c;                              // c identical across all threads
        if ((t & 3) == 0) { ll += __logf(lp); lp = 1.f; }
        float anew = s * em * __builtin_amdgcn_rcpf(c);

        // prefetch operands for t+1 (independent of this step's barrier)
        em = (float)Bt[o_nx * NS + j];
        const char* drow = (const char*)&sD[o_nx * DPAD];
#pragma unroll
        for (int q = 0; q < 8; ++q) dv[q] = *(const float4*)(drow + boff + 16 * q);
        dt = *(const float2*)(drow + toff);
        o_nx = (t + 2 < TLEN) ? (int)ob[t + 2] : 0;

        // pin the prefetched operands on THIS side of the barrier
#pragma unroll
        for (int q = 0; q < 8; ++q) {
            KEEP(dv[q].x); KEEP(dv[q].y); KEEP(dv[q].z); KEEP(dv[q].w);
        }
        KEEP(dt.x); KEEP(dt.y); KEEP(em);

        if (active && h == 0) sAl[cur ^ 1][j] = (half_t)anew;
        __syncthreads();
        cur ^= 1;
    }

    ll += __logf(lp);
    if (tid == 0) out[b] = ll;
}

// ---------------------------------------------------------------------------
extern "C" void kernel_launch(void* const* d_in, const int* in_sizes, int n_in,
                              void* d_out, int out_size, void* d_ws, size_t ws_size,
                              hipStream_t stream) {
    const float* x  = (const float*)d_in[0];  // [32,10000,126] one-hot fp32
    const float* A  = (const float*)d_in[1];  // [132,132]
    const float* Bm = (const float*)d_in[2];  // [132,126]
    const float* I0 = (const float*)d_in[3];  // [132]
    float* out = (float*)d_out;               // [32] fp32

    char* ws = (char*)d_ws;
    unsigned short* obs = (unsigned short*)(ws + OBS_OFF);
    h2*     Ah = (h2*)(ws + AH_OFF);
    half_t* Bt = (half_t*)(ws + BT_OFF);
    half_t* Dh = (half_t*)(ws + DH_OFF);

    const int total = NBATCH * TLEN;
    onehot_to_idx_kernel<<<(total + 3) / 4, 256, 0, stream>>>(x, obs, total);
    pack_A_kernel<<<(NI2 * NS + 255) / 256, 256, 0, stream>>>(A, Ah);
    pack_Bt_kernel<<<(NA * NS + 255) / 256, 256, 0, stream>>>(Bm, Bt);
    make_D_kernel<<<NA, 192, 0, stream>>>(A, Bm, Dh);
    hmm_forward_kernel<<<NBATCH, 320, 0, stream>>>(Ah, Bt, Dh, I0, obs, out);
}

// Round 4
// 5498.370 us; speedup vs baseline: 1.4764x; 1.1682x over previous
//
#include <hip/hip_runtime.h>

// ---------------------------------------------------------------------------
// Scaled HMM forward, B=32 rows, T=10000 serial steps, N=132 states.
// ROUND-4 REDESIGN: round 2/3 were LDS-*instruction-throughput* bound:
// 5 waves x 18 ds_read_b128/step = 90 LDS instrs x ~12cy = ~1080cy of the
// measured 1536cy/step (one block per CU -> one LDS pipe).
// New structure: 3 waves (thread j = state j, full-K dot per thread).
//  - alpha distributed 1 h2-pair per lane; 2 ds_read_b32 per wave per step
//  - broadcast via v_readlane -> SGPR operand of v_dot2_f32_f16
//  - c_t = sum(y) via pair-dot + 6-stage shfl tree (DS pipe, overlaps the
//    VALU dot phase; consumed with 1-step lag, exact log accounting)
//  - A column (66 h2) pinned via volatile-asm v_mov defs (cannot remat)
//  - ONE barrier per step
// ---------------------------------------------------------------------------

typedef _Float16 half_t;
typedef half_t h2 __attribute__((ext_vector_type(2)));

#define FDOT2(a, b, acc) __builtin_amdgcn_fdot2((a), (b), (acc), false)

#define NS 132
#define NA 126
#define NI2 66        // h2 pairs along K
#define JPAD 192      // padded state dimension (3 waves x 64)
#define YPAD 256      // halves per alpha row (512 B; pairs 0..127 readable)
#define TLEN 10000
#define NBATCH 32

// workspace layout (bytes)
#define OBS_OFF 0         // 32*10000 ushort = 640000
#define AH_OFF  640000    // 66*192 h2 (4B)  = 50688
#define BT_OFF  690688    // 126*192 half    = 48384

// ---------------------------------------------------------------------------
__global__ void onehot_to_idx_kernel(const float* __restrict__ x,
                                     unsigned short* __restrict__ obs, int total) {
    int wid  = (int)((blockIdx.x * blockDim.x + threadIdx.x) >> 6);
    int lane = threadIdx.x & 63;
    if (wid >= total) return;
    const float* row = x + (size_t)wid * NA;
    float v0 = row[lane];
    float v1 = (lane < NA - 64) ? row[64 + lane] : 0.0f;
    unsigned long long b0 = __ballot(v0 > 0.5f);
    unsigned long long b1 = __ballot(v1 > 0.5f);
    int idx = b0 ? (__ffsll(b0) - 1) : (64 + __ffsll(b1) - 1);
    if (lane == 0) obs[wid] = (unsigned short)idx;
}

// Ah[i2*JPAD + j] = (f16(A[2i2][j]), f16(A[2i2+1][j])), 0 for j >= NS
__global__ void pack_A_kernel(const float* __restrict__ A, h2* __restrict__ Ah) {
    int idx = blockIdx.x * 256 + threadIdx.x;
    if (idx >= NI2 * JPAD) return;
    int i2 = idx / JPAD, j = idx % JPAD;
    h2 v = {(half_t)0.f, (half_t)0.f};
    if (j < NS) {
        v.x = (half_t)A[(2 * i2) * NS + j];
        v.y = (half_t)A[(2 * i2 + 1) * NS + j];
    }
    Ah[idx] = v;
}

// Btp[o*JPAD + j] = f16(B[j][o]), 0 for j >= NS
__global__ void pack_Bt_kernel(const float* __restrict__ B, half_t* __restrict__ Btp) {
    int idx = blockIdx.x * 256 + threadIdx.x;
    if (idx >= NA * JPAD) return;
    int o = idx / JPAD, j = idx % JPAD;
    Btp[idx] = (j < NS) ? (half_t)B[j * NA + o] : (half_t)0.f;
}

// ---------------------------------------------------------------------------
// Serial scan: 32 blocks x 192 threads (3 waves). Thread j owns state j.
// ---------------------------------------------------------------------------
__global__ __launch_bounds__(192, 1)
__attribute__((amdgpu_waves_per_eu(1, 1)))
void hmm_forward_kernel(
    const h2* __restrict__ Ah,        // [66][192]
    const half_t* __restrict__ Btp,   // [126][192]
    const float* __restrict__ I0,     // [132]
    const unsigned short* __restrict__ obs,
    float* __restrict__ out)
{
    __shared__ __align__(16) half_t sB[NA * JPAD];   // 48384 B
    __shared__ __align__(16) half_t sY[2][YPAD];     // 1024 B alpha dbuf

    const int tid  = threadIdx.x;
    const int b    = blockIdx.x;
    const int lane = tid & 63;
    const int j    = tid;            // state (0..191; >=132 are zero-padded)

    // stage emission table into LDS (3024 float4)
    {
        const float4* src = (const float4*)Btp;
        float4* dst = (float4*)sB;
        for (int k = tid; k < (NA * JPAD) / 8; k += 192) dst[k] = src[k];
    }
    // zero both alpha rows (incl. pads) once
    {
        float* z = (float*)&sY[0][0];
        for (int k = tid; k < (2 * YPAD) / 2; k += 192) z[k] = 0.f;
    }

    // A column j as 66 f16-pairs, pinned via volatile-asm defs (cannot be
    // rematerialized; a scratch spill would show up in FETCH/WRITE counters)
    h2 rA[NI2];
#pragma unroll
    for (int i = 0; i < NI2; ++i) {
        h2 t = Ah[i * JPAD + j];
        asm volatile("v_mov_b32 %0, %1" : "=v"(rA[i]) : "v"(t));
    }

    const unsigned short* ob = obs + b * TLEN;
    int o0 = (int)ob[0];
    int o1 = (int)ob[1];
    float i0v = (j < NS) ? I0[j] : 0.f;
    __syncthreads();

    // ---- t = 0: y0 = 128 * I0 * B[:,o0]  (sum ~1; log-accounted below) ----
    float em0 = (float)sB[o0 * JPAD + j];
    sY[0][j] = (half_t)(i0v * em0 * 128.0f);
    float em = (float)sB[o1 * JPAD + j];     // prefetch emission for t = 1
    int o_nx = (int)ob[2];
    __syncthreads();

    const h2 ones = {(half_t)1.0f, (half_t)1.0f};
    float ll = 0.f, lp = 1.f;
    int cur = 0;

    for (int t = 1; t < TLEN; ++t) {
        // read alpha pairs: lane holds pair `lane` and pair `64+lane`
        const float* yrow = (const float*)&sY[cur][0];
        float r0f = yrow[lane];
        float r1f = yrow[64 + lane];
        h2 r0 = __builtin_bit_cast(h2, r0f);
        h2 r1 = __builtin_bit_cast(h2, r1f);

        // red = sum(y_{t-1}): pair sums + xor tree (DS pipe, overlaps dots)
        float ps = FDOT2(r0, ones, FDOT2(r1, ones, 0.f));
#pragma unroll
        for (int off = 32; off; off >>= 1) ps += __shfl_xor(ps, off, 64);

        // s_j = sum_i y_i * A[i][j] via readlane-broadcast + dot2
        int a0i = __builtin_bit_cast(int, r0f);
        int a1i = __builtin_bit_cast(int, r1f);
        float s0 = 0.f, s1 = 0.f, s2 = 0.f, s3 = 0.f;
#pragma unroll
        for (int i2 = 0; i2 < 16; ++i2) {
            h2 xa0 = __builtin_bit_cast(h2, __builtin_amdgcn_readlane(a0i, 4 * i2 + 0));
            h2 xa1 = __builtin_bit_cast(h2, __builtin_amdgcn_readlane(a0i, 4 * i2 + 1));
            h2 xa2 = __builtin_bit_cast(h2, __builtin_amdgcn_readlane(a0i, 4 * i2 + 2));
            h2 xa3 = __builtin_bit_cast(h2, __builtin_amdgcn_readlane(a0i, 4 * i2 + 3));
            s0 = FDOT2(xa0, rA[4 * i2 + 0], s0);
            s1 = FDOT2(xa1, rA[4 * i2 + 1], s1);
            s2 = FDOT2(xa2, rA[4 * i2 + 2], s2);
            s3 = FDOT2(xa3, rA[4 * i2 + 3], s3);
        }
        {   // pairs 64, 65 live in r1 at lanes 0, 1
            h2 xa0 = __builtin_bit_cast(h2, __builtin_amdgcn_readlane(a1i, 0));
            h2 xa1 = __builtin_bit_cast(h2, __builtin_amdgcn_readlane(a1i, 1));
            s0 = FDOT2(xa0, rA[64], s0);
            s1 = FDOT2(xa1, rA[65], s1);
        }
        float s = (s0 + s1) + (s2 + s3);
        float a = s * em;

        // scale to sum ~1 with 128/red_{t-1}; account log(red) exactly
        float g = 128.0f * __builtin_amdgcn_rcpf(ps);
        lp *= ps;
        if ((t & 3) == 0) { ll += __logf(lp); lp = 1.f; }

        // prefetch next emission + next-next observation
        float em_nx = (float)sB[o_nx * JPAD + j];
        int o_nx2 = (t + 2 < TLEN) ? (int)ob[t + 2] : 0;

        sY[cur ^ 1][j] = (half_t)(a * g);
        __syncthreads();

        em = em_nx;
        o_nx = o_nx2;
        cur ^= 1;
    }
    ll += __logf(lp);

    // epilogue: + log(sum(y_T)) - 10000*log(128)
    {
        const float* yrow = (const float*)&sY[cur][0];
        float r0f = yrow[lane];
        float r1f = yrow[64 + lane];
        float ps = FDOT2(__builtin_bit_cast(h2, r0f), ones,
                         FDOT2(__builtin_bit_cast(h2, r1f), ones, 0.f));
#pragma unroll
        for (int off = 32; off; off >>= 1) ps += __shfl_xor(ps, off, 64);
        ll += __logf(ps);
    }
    ll -= 48520.302631459f;   // 10000 * log(128)

    if (tid == 0) out[b] = ll;
}

// ---------------------------------------------------------------------------
extern "C" void kernel_launch(void* const* d_in, const int* in_sizes, int n_in,
                              void* d_out, int out_size, void* d_ws, size_t ws_size,
                              hipStream_t stream) {
    const float* x  = (const float*)d_in[0];  // [32,10000,126] one-hot fp32
    const float* A  = (const float*)d_in[1];  // [132,132]
    const float* Bm = (const float*)d_in[2];  // [132,126]
    const float* I0 = (const float*)d_in[3];  // [132]
    float* out = (float*)d_out;               // [32] fp32

    char* ws = (char*)d_ws;
    unsigned short* obs = (unsigned short*)(ws + OBS_OFF);
    h2*     Ah  = (h2*)(ws + AH_OFF);
    half_t* Btp = (half_t*)(ws + BT_OFF);

    const int total = NBATCH * TLEN;
    onehot_to_idx_kernel<<<(total + 3) / 4, 256, 0, stream>>>(x, obs, total);
    pack_A_kernel<<<(NI2 * JPAD + 255) / 256, 256, 0, stream>>>(A, Ah);
    pack_Bt_kernel<<<(NA * JPAD + 255) / 256, 256, 0, stream>>>(Bm, Btp);
    hmm_forward_kernel<<<NBATCH, 192, 0, stream>>>(Ah, Btp, I0, obs, out);
}